// Round 4
// baseline (280.097 us; speedup 1.0000x reference)
//
#include <hip/hip_runtime.h>

#define NT 8192      // tokens
#define CD 512       // C_K = C_V = 512
#define NH 8         // heads
#define KQV_LD 1536  // fused output width
#define SC_N 8192

using f32x4  = __attribute__((ext_vector_type(4))) float;
using bf16x8 = __attribute__((ext_vector_type(8))) __bf16;

__device__ __forceinline__ unsigned short f2bf(float x) {
    union { float f; unsigned u; } c; c.f = x;
    unsigned r = c.u + 0x7fffu + ((c.u >> 16) & 1u);
    return (unsigned short)(r >> 16);
}
__device__ __forceinline__ float bf2f(unsigned short b) {
    union { float f; unsigned u; } c; c.u = ((unsigned)b) << 16;
    return c.f;
}

// ---------------- prep kernels ----------------

__global__ void cvt_input_k(const float4* __restrict__ in, unsigned short* __restrict__ out) {
    int i = blockIdx.x * 256 + threadIdx.x;   // 1048576 threads
    float4 v = in[i];
    out[i*4+0] = f2bf(v.x);
    out[i*4+1] = f2bf(v.y);
    out[i*4+2] = f2bf(v.z);
    out[i*4+3] = f2bf(v.w);
}

__global__ void prep_w_k(const float* __restrict__ Wk, const float* __restrict__ Wq,
                         const float* __restrict__ Wv, const float* __restrict__ bk,
                         const float* __restrict__ bq, const float* __restrict__ bv,
                         unsigned short* __restrict__ Wt, float* __restrict__ biaskqv) {
    int idx = blockIdx.x * 256 + threadIdx.x;   // 1536*512
    int c = idx >> 9, k = idx & 511;
    int sec = c >> 9, cc = c & 511;
    const float* W = (sec == 0) ? Wk : ((sec == 1) ? Wq : Wv);
    Wt[idx] = f2bf(W[k * 512 + cc]);
    if (idx < 1536) {
        const float* b = (idx < 512) ? bk : ((idx < 1024) ? bq : bv);
        biaskqv[idx] = b[idx & 511];
    }
}

// ---------------- m97-style GEMM: C[M,N] = alpha * A[M,K] @ Bt[N,K]^T + bias[N] ----------------
__global__ __launch_bounds__(256) void gemm_bt(
    const unsigned short* __restrict__ A, const unsigned short* __restrict__ Bt,
    float* __restrict__ C, const float* __restrict__ bias,
    int M, int N, int K, float alpha)
{
    __shared__ unsigned short sA[128 * 32];
    __shared__ unsigned short sB[128 * 32];
    const int tid  = threadIdx.x;
    const int wid  = tid >> 6;
    const int lane = tid & 63;
    const int col0 = blockIdx.x * 128;
    const int row0 = blockIdx.y * 128;
    const int wr = (wid >> 1) * 64;
    const int wc = (wid & 1) * 64;
    const int fr = lane & 15;
    const int fq = lane >> 4;
    const int srow = lane >> 2;
    const int scol = (lane & 3) * 8;

    f32x4 acc[4][4] = {};

    const int kTiles = K >> 5;
    for (int kt = 0; kt < kTiles; ++kt) {
        const int k0 = kt << 5;
        __syncthreads();
        #pragma unroll
        for (int s = 0; s < 2; ++s) {
            const int seg = wid * 2 + s;
            const unsigned short* gA = A + (size_t)(row0 + seg * 16 + srow) * K + k0 + scol;
            __builtin_amdgcn_global_load_lds(
                (const __attribute__((address_space(1))) void*)gA,
                (__attribute__((address_space(3))) void*)(sA + seg * 512), 16, 0, 0);
            const unsigned short* gB = Bt + (size_t)(col0 + seg * 16 + srow) * K + k0 + scol;
            __builtin_amdgcn_global_load_lds(
                (const __attribute__((address_space(1))) void*)gB,
                (__attribute__((address_space(3))) void*)(sB + seg * 512), 16, 0, 0);
        }
        __syncthreads();

        bf16x8 av[4], bfrag[4];
        #pragma unroll
        for (int m = 0; m < 4; ++m)
            av[m] = *(const bf16x8*)(sA + (wr + m * 16 + fr) * 32 + fq * 8);
        #pragma unroll
        for (int n = 0; n < 4; ++n)
            bfrag[n] = *(const bf16x8*)(sB + (wc + n * 16 + fr) * 32 + fq * 8);
        #pragma unroll
        for (int m = 0; m < 4; ++m)
            #pragma unroll
            for (int n = 0; n < 4; ++n)
                acc[m][n] = __builtin_amdgcn_mfma_f32_16x16x32_bf16(av[m], bfrag[n], acc[m][n], 0, 0, 0);
    }

    #pragma unroll
    for (int n = 0; n < 4; ++n) {
        const int col = col0 + wc + n * 16 + fr;
        const float bval = bias ? bias[col] : 0.f;
        #pragma unroll
        for (int m = 0; m < 4; ++m) {
            #pragma unroll
            for (int r = 0; r < 4; ++r) {
                const int row = row0 + wr + m * 16 + fq * 4 + r;
                C[(size_t)row * N + col] = acc[m][n][r] * alpha + bval;
            }
        }
    }
}

// ---------------- scores GEMM: m201-style 8-phase, 256x256 tile, BK=64 ----------------
// C[8192,8192] = 0.125 * A[8192,512] @ B[8192,512]^T
// LDS = ring of 8 half-slots (128 rows x 64 k bf16 = 16KB each). Half-tile sequence
// h = 4T+j, j: 0=Bh0 1=Bh1 2=Ah0 3=Ah1; slot = h&7. Tick p (= 4T+L) stages h=p+7.
// Reads: B(all 8 frags)@L0, A(mf0-3)@L0, A(mf4-7)@L2 -> every slot's reads end
// strictly before its restage tick (restage of slot j at tick 4T+j+1).
// vmcnt(6) only at L3 ticks: covers tile T+1's halves (staged <= tick 4T-4+4).
__global__ __launch_bounds__(512) void scores8p_k(
    const unsigned short* __restrict__ A, const unsigned short* __restrict__ B,
    float* __restrict__ C)
{
    __shared__ unsigned short lds[8][8192];   // 128 KiB
    const int tid  = threadIdx.x;
    const int wid  = tid >> 6;
    const int lane = tid & 63;
    const int fr = lane & 15;
    const int fq = lane >> 4;
    const int wm = wid >> 2;      // 0..1 -> 128-row half of A-tile
    const int wn = wid & 3;       // 0..3 -> 64-col quarter of B-tile
    const int bh = wn >> 1;       // which B half-slot this wave reads

    // bijective XCD swizzle (1024 % 8 == 0) + L2 grouping (verified R2/R3)
    int g = blockIdx.x;
    g = (g & 7) * 128 + (g >> 3);
    const int by = (g & 7) + ((g >> 8) << 3);
    const int bx = (g >> 3) & 31;
    const int row0 = by * 256, col0 = bx * 256;

    // staging pre-swizzle: physical 16B unit i holds logical (row=i>>3, cu=(i&7)^(row&7))
    int prow[2], pk8[2];
    #pragma unroll
    for (int l = 0; l < 2; ++l) {
        int i = l * 512 + tid;
        prow[l] = i >> 3;
        pk8[l]  = ((i & 7) ^ ((i >> 3) & 7)) << 3;
    }

    f32x4 acc[8][4] = {};
    bf16x8 a03[8], a47[8], b01[4], b23[4];

    auto STAGE = [&](int T, int j) {   // stage half-tile (T, j); T,j compile-time
        const int slot = ((T & 1) << 2) | j;
        const unsigned short* src = (j >= 2) ? A : B;
        const int rb = ((j >= 2) ? row0 : col0) + ((j & 1) << 7);
        #pragma unroll
        for (int l = 0; l < 2; ++l) {
            const unsigned short* gp = src + (size_t)(rb + prow[l]) * 512 + T * 64 + pk8[l];
            __builtin_amdgcn_global_load_lds(
                (const __attribute__((address_space(1))) void*)gp,
                (__attribute__((address_space(3))) void*)((char*)&lds[slot][0] + ((l * 512 + wid * 64) << 4)),
                16, 0, 0);
        }
    };
    auto LD_A = [&](int T, int mfb, bf16x8* r8) {
        const char* base = (const char*)&lds[((T & 1) << 2) | 2 | wm][0];
        #pragma unroll
        for (int mf = 0; mf < 4; ++mf)
            #pragma unroll
            for (int ks = 0; ks < 2; ++ks) {
                int rr = (mfb + mf) * 16 + fr;
                int cu = ks * 4 + fq;
                r8[mf * 2 + ks] = *(const bf16x8*)(base + ((rr * 8 + (cu ^ (rr & 7))) << 4));
            }
    };
    auto LD_B = [&](int T, int nfb, bf16x8* r4) {
        const char* base = (const char*)&lds[((T & 1) << 2) | bh][0];
        #pragma unroll
        for (int nf = 0; nf < 2; ++nf)
            #pragma unroll
            for (int ks = 0; ks < 2; ++ks) {
                int rr = ((wn & 1) << 6) + (nfb + nf) * 16 + fr;
                int cu = ks * 4 + fq;
                r4[nf * 2 + ks] = *(const bf16x8*)(base + ((rr * 8 + (cu ^ (rr & 7))) << 4));
            }
    };
    auto MFMA16 = [&](int mfb, int nfb, const bf16x8* ra, const bf16x8* rb) {
        __builtin_amdgcn_s_setprio(1);
        #pragma unroll
        for (int mf = 0; mf < 4; ++mf)
            #pragma unroll
            for (int nf = 0; nf < 2; ++nf)
                #pragma unroll
                for (int ks = 0; ks < 2; ++ks)
                    acc[mfb + mf][nfb + nf] = __builtin_amdgcn_mfma_f32_16x16x32_bf16(
                        ra[mf * 2 + ks], rb[nf * 2 + ks], acc[mfb + mf][nfb + nf], 0, 0, 0);
        __builtin_amdgcn_s_setprio(0);
    };
    auto BAR = [&]() {
        __builtin_amdgcn_s_barrier();
        __builtin_amdgcn_sched_barrier(0);
    };

    // prologue: stage halves h = 0..6 (tile 0 complete + Bh0,Bh1,Ah0 of tile 1)
    STAGE(0, 0); STAGE(0, 1); STAGE(0, 2); STAGE(0, 3);
    STAGE(1, 0); STAGE(1, 1); STAGE(1, 2);
    asm volatile("s_waitcnt vmcnt(6)" ::: "memory");   // tile 0 resident
    BAR();

    #pragma unroll
    for (int T = 0; T < 8; ++T) {
        // ---- tick L0 ----
        LD_A(T, 0, a03); LD_B(T, 0, b01); LD_B(T, 2, b23);
        { constexpr int dummy = 0; int h = 4 * T + 7; if (h < 32) STAGE(h >> 2, h & 3); (void)dummy; }
        BAR();
        MFMA16(0, 0, a03, b01);
        BAR();
        // ---- tick L1 ----
        { int h = 4 * T + 8; if (h < 32) STAGE(h >> 2, h & 3); }
        BAR();
        MFMA16(0, 2, a03, b23);
        BAR();
        // ---- tick L2 ----
        LD_A(T, 4, a47);
        { int h = 4 * T + 9; if (h < 32) STAGE(h >> 2, h & 3); }
        BAR();
        MFMA16(4, 0, a47, b01);
        BAR();
        // ---- tick L3 ----
        { int h = 4 * T + 10; if (h < 32) STAGE(h >> 2, h & 3); }
        BAR();
        MFMA16(4, 2, a47, b23);
        if (T < 6)       asm volatile("s_waitcnt vmcnt(6)" ::: "memory");  // tile T+1 resident
        else if (T == 6) asm volatile("s_waitcnt vmcnt(0)" ::: "memory");  // tile 7 resident
        BAR();
    }

    #pragma unroll
    for (int mf = 0; mf < 8; ++mf) {
        const int rowb = row0 + wm * 128 + mf * 16 + fq * 4;
        #pragma unroll
        for (int nf = 0; nf < 4; ++nf) {
            const int col = col0 + wn * 64 + nf * 16 + fr;
            #pragma unroll
            for (int r = 0; r < 4; ++r)
                C[(size_t)(rowb + r) * SC_N + col] = acc[mf][nf][r] * 0.125f;
        }
    }
}

// ---------------- key softmax (over tokens, per column), fused online max+sum ----------------

__global__ void colms_partial_k(const float* __restrict__ KQV,
                                float* __restrict__ pmax, float* __restrict__ psum) {
    int c = threadIdx.x;       // 512 threads
    int b = blockIdx.x;        // 256 blocks x 32 rows
    const float* p = KQV + (size_t)b * 32 * KQV_LD + c;
    float m = -1e30f, s = 0.f;
    for (int r = 0; r < 32; ++r) {
        float x = p[(size_t)r * KQV_LD];
        if (x > m) { s = s * __expf(m - x) + 1.f; m = x; }
        else s += __expf(x - m);
    }
    pmax[b * 512 + c] = m;
    psum[b * 512 + c] = s;
}
__global__ void colms_final_k(const float* __restrict__ pmax, const float* __restrict__ psum,
                              float* __restrict__ cmax, float* __restrict__ crcp) {
    int c = blockIdx.x * 256 + threadIdx.x;   // 512 total
    float m = -1e30f;
    for (int b = 0; b < 256; ++b) m = fmaxf(m, pmax[b * 512 + c]);
    float s = 0.f;
    for (int b = 0; b < 256; ++b) s += psum[b * 512 + c] * __expf(pmax[b * 512 + c] - m);
    cmax[c] = m;
    crcp[c] = 1.f / s;
}
__global__ void ksm_k(const float* __restrict__ KQV, const float* __restrict__ cmax,
                      const float* __restrict__ crcp, unsigned short* __restrict__ ksm) {
    int idx = blockIdx.x * 256 + threadIdx.x;   // 8192*512
    int n = idx >> 9, c = idx & 511;
    float x = __expf(KQV[(size_t)n * KQV_LD + c] - cmax[c]) * crcp[c];
    ksm[idx] = f2bf(x);
}

// ---------------- query softmax (over 64 channels) + v convert ----------------
__global__ void qsm_v_k(const float* __restrict__ KQV, unsigned short* __restrict__ qsm,
                        unsigned short* __restrict__ vbf) {
    int gw = (blockIdx.x * 256 + threadIdx.x) >> 6;   // wave id, 65536 total
    int lane = threadIdx.x & 63;
    int n = gw >> 3, h = gw & 7;
    float q = KQV[(size_t)n * KQV_LD + 512 + h * 64 + lane];
    float m = q;
    #pragma unroll
    for (int off = 32; off; off >>= 1) m = fmaxf(m, __shfl_xor(m, off));
    float e = __expf(q - m);
    float s = e;
    #pragma unroll
    for (int off = 32; off; off >>= 1) s += __shfl_xor(s, off);
    qsm[(size_t)gw * 64 + lane] = f2bf(e / s);
    vbf[(size_t)gw * 64 + lane] = f2bf(KQV[(size_t)n * KQV_LD + 1024 + h * 64 + lane]);
}

// ---------------- context = k_sm^T @ v per head via MFMA on LDS-transposed tiles ----------------
__global__ __launch_bounds__(256) void context_partial_k(
    const unsigned short* __restrict__ ksm, const unsigned short* __restrict__ vbf,
    float* __restrict__ pctx)
{
    const int ch = blockIdx.x;   // 32 chunks x 256 rows
    const int h  = blockIdx.y;   // 8 heads
    const int tid = threadIdx.x, w = tid >> 6, lane = tid & 63;
    const int fr = lane & 15, fq = lane >> 4;
    __shared__ unsigned short tr[4][2][4096];   // [wave][k/v][64 kchan * 64 tok] = 64 KiB
    char* kt = (char*)&tr[w][0][0];
    char* vt = (char*)&tr[w][1][0];
    const int nbase = ch * 256 + w * 64;

    #pragma unroll
    for (int j = 0; j < 8; ++j) {
        bf16x8 kv = *(const bf16x8*)(ksm + (size_t)(nbase + lane) * 512 + h * 64 + j * 8);
        bf16x8 vv = *(const bf16x8*)(vbf + (size_t)(nbase + lane) * 512 + h * 64 + j * 8);
        #pragma unroll
        for (int e = 0; e < 8; ++e) {
            int k = j * 8 + e;
            int byte = (k * 128 + lane * 2) ^ (e << 4);   // k&7 == e
            *(unsigned short*)(kt + byte) = ((const unsigned short*)&kv)[e];
            *(unsigned short*)(vt + byte) = ((const unsigned short*)&vv)[e];
        }
    }
    asm volatile("s_waitcnt lgkmcnt(0)" ::: "memory");
    __builtin_amdgcn_sched_barrier(0);

    f32x4 acc[4][4] = {};
    #pragma unroll
    for (int ks = 0; ks < 2; ++ks) {
        bf16x8 a[4], b[4];
        #pragma unroll
        for (int mf = 0; mf < 4; ++mf) {
            int row  = mf * 16 + fr;
            int byte = (row * 128 + (ks * 4 + fq) * 16) ^ ((row & 7) << 4);
            a[mf] = *(const bf16x8*)(kt + byte);
            b[mf] = *(const bf16x8*)(vt + byte);
        }
        #pragma unroll
        for (int mf = 0; mf < 4; ++mf)
            #pragma unroll
            for (int nf = 0; nf < 4; ++nf)
                acc[mf][nf] = __builtin_amdgcn_mfma_f32_16x16x32_bf16(a[mf], b[nf], acc[mf][nf], 0, 0, 0);
    }

    float* out = pctx + (size_t)((ch * 4 + w) * 8 + h) * 4096;
    #pragma unroll
    for (int mf = 0; mf < 4; ++mf)
        #pragma unroll
        for (int nf = 0; nf < 4; ++nf)
            #pragma unroll
            for (int r = 0; r < 4; ++r)
                out[(mf * 16 + fq * 4 + r) * 64 + nf * 16 + fr] = acc[mf][nf][r];
}
__global__ void context_reduce_k(const float* __restrict__ pctx, float* __restrict__ ctx) {
    int idx = blockIdx.x * 256 + threadIdx.x;   // 8*4096 = 32768
    int h = idx >> 12, e = idx & 4095;
    float s = 0.f;
    for (int p = 0; p < 128; ++p) s += pctx[(size_t)(p * 8 + h) * 4096 + e];
    ctx[idx] = s;
}

// ---------------- Mt[o][h*64+k] = sum_j ctx[h][k][j] * Wr[h*64+j][o]  (bf16) ----------------
__global__ void mt_k(const float* __restrict__ ctx, const float* __restrict__ Wr,
                     unsigned short* __restrict__ Mt) {
    int idx = blockIdx.x * 256 + threadIdx.x;   // 512*512
    int o = idx >> 9, hk = idx & 511;
    int h = hk >> 6, k = hk & 63;
    float s = 0.f;
    for (int j = 0; j < 64; ++j)
        s += ctx[h * 4096 + k * 64 + j] * Wr[(size_t)(h * 64 + j) * 512 + o];
    Mt[(size_t)o * 512 + hk] = f2bf(s);
}

// ---------------- launch ----------------
extern "C" void kernel_launch(void* const* d_in, const int* in_sizes, int n_in,
                              void* d_out, int out_size, void* d_ws, size_t ws_size,
                              hipStream_t stream) {
    const float* input = (const float*)d_in[0];
    const float* Wk = (const float*)d_in[1];
    const float* bk = (const float*)d_in[2];
    const float* Wq = (const float*)d_in[3];
    const float* bq = (const float*)d_in[4];
    const float* Wv = (const float*)d_in[5];
    const float* bv = (const float*)d_in[6];
    const float* Wr = (const float*)d_in[7];
    const float* br = (const float*)d_in[8];

    char* ws = (char*)d_ws;
    unsigned short* inp_bf = (unsigned short*)ws;  ws += (size_t)NT * CD * 2;
    unsigned short* Wt     = (unsigned short*)ws;  ws += (size_t)1536 * 512 * 2;
    float* biaskqv         = (float*)ws;           ws += 1536 * 4;
    float* KQV             = (float*)ws;           ws += (size_t)NT * KQV_LD * 4;
    float* pmax            = (float*)ws;           ws += 256 * 512 * 4;
    float* cmax            = (float*)ws;           ws += 512 * 4;
    float* psum            = (float*)ws;           ws += 256 * 512 * 4;
    float* crcp            = (float*)ws;           ws += 512 * 4;
    unsigned short* ksm    = (unsigned short*)ws;  ws += (size_t)NT * CD * 2;
    unsigned short* qsm    = (unsigned short*)ws;  ws += (size_t)NT * CD * 2;
    unsigned short* vbf    = (unsigned short*)ws;  ws += (size_t)NT * CD * 2;
    float* ctx             = (float*)ws;           ws += (size_t)8 * 4096 * 4;
    unsigned short* Mt     = (unsigned short*)ws;  ws += (size_t)512 * 512 * 2;
    // pctx (16.8 MB) aliases KQV (50.3 MB): KQV is dead once ksm/qsm/vbf exist.
    float* pctx = KQV;

    float* attn_out   = (float*)d_out;
    float* scores_out = (float*)d_out + (size_t)NT * CD;

    cvt_input_k<<<4096, 256, 0, stream>>>((const float4*)input, inp_bf);
    prep_w_k<<<3072, 256, 0, stream>>>(Wk, Wq, Wv, bk, bq, bv, Wt, biaskqv);

    gemm_bt<<<dim3(12, 64), 256, 0, stream>>>(inp_bf, Wt, KQV, biaskqv, NT, KQV_LD, CD, 1.0f);

    colms_partial_k<<<256, 512, 0, stream>>>(KQV, pmax, psum);
    colms_final_k<<<2, 256, 0, stream>>>(pmax, psum, cmax, crcp);
    ksm_k<<<16384, 256, 0, stream>>>(KQV, cmax, crcp, ksm);
    qsm_v_k<<<16384, 256, 0, stream>>>(KQV, qsm, vbf);

    context_partial_k<<<dim3(32, 8), 256, 0, stream>>>(ksm, vbf, pctx);
    context_reduce_k<<<128, 256, 0, stream>>>(pctx, ctx);
    mt_k<<<1024, 256, 0, stream>>>(ctx, Wr, Mt);

    gemm_bt<<<dim3(4, 64), 256, 0, stream>>>(qsm, Mt, attn_out, br, NT, CD, CD, 1.0f);
    scores8p_k<<<1024, 512, 0, stream>>>(qsm, ksm, scores_out);
}

// Round 5
// 233.997 us; speedup vs baseline: 1.1970x; 1.1970x over previous
//
#include <hip/hip_runtime.h>

#define NT 8192      // tokens
#define CD 512       // C_K = C_V = 512
#define NH 8         // heads
#define SC_N 8192

using f32x4  = __attribute__((ext_vector_type(4))) float;
using bf16x8 = __attribute__((ext_vector_type(8))) __bf16;

__device__ __forceinline__ unsigned short f2bf(float x) {
    union { float f; unsigned u; } c; c.f = x;
    unsigned r = c.u + 0x7fffu + ((c.u >> 16) & 1u);
    return (unsigned short)(r >> 16);
}
__device__ __forceinline__ float bf2f(unsigned short b) {
    union { float f; unsigned u; } c; c.u = ((unsigned)b) << 16;
    return c.f;
}

// ---------------- prep kernels ----------------

__global__ void cvt_input_k(const float4* __restrict__ in, unsigned short* __restrict__ out) {
    int i = blockIdx.x * 256 + threadIdx.x;   // 1048576 threads
    float4 v = in[i];
    out[i*4+0] = f2bf(v.x);
    out[i*4+1] = f2bf(v.y);
    out[i*4+2] = f2bf(v.z);
    out[i*4+3] = f2bf(v.w);
}

__global__ void prep_w_k(const float* __restrict__ Wk, const float* __restrict__ Wq,
                         const float* __restrict__ Wv, const float* __restrict__ bk,
                         const float* __restrict__ bq, const float* __restrict__ bv,
                         unsigned short* __restrict__ Wt, float* __restrict__ biaskqv) {
    int idx = blockIdx.x * 256 + threadIdx.x;   // 1536*512
    int c = idx >> 9, k = idx & 511;
    int sec = c >> 9, cc = c & 511;
    const float* W = (sec == 0) ? Wk : ((sec == 1) ? Wq : Wv);
    Wt[idx] = f2bf(W[k * 512 + cc]);
    if (idx < 1536) {
        const float* b = (idx < 512) ? bk : ((idx < 1024) ? bq : bv);
        biaskqv[idx] = b[idx & 511];
    }
}

// ---------------- KQV GEMM with fused epilogues ----------------
// [8192,1536] = inp_bf[8192,512] @ Wt[1536,512]^T + bias. m97 structure.
// Section by col0: 0-511 keys -> kbf bf16 + per-64-row col max/sumexp partials;
// 512-1023 queries -> row softmax (wave-local) -> qsm bf16 FINAL;
// 1024-1535 values -> vbf bf16 FINAL.
__global__ __launch_bounds__(256) void kqv_gemm_k(
    const unsigned short* __restrict__ A, const unsigned short* __restrict__ Bt,
    const float* __restrict__ bias,
    unsigned short* __restrict__ kbf, unsigned short* __restrict__ qsm,
    unsigned short* __restrict__ vbf,
    float* __restrict__ pmax, float* __restrict__ psum)
{
    __shared__ unsigned short sA[128 * 32];
    __shared__ unsigned short sB[128 * 32];
    const int tid  = threadIdx.x;
    const int wid  = tid >> 6;
    const int lane = tid & 63;
    const int col0 = blockIdx.x * 128;     // 0..1535
    const int row0 = blockIdx.y * 128;
    const int by   = blockIdx.y;
    const int wr = (wid >> 1) * 64;
    const int wc = (wid & 1) * 64;
    const int fr = lane & 15;
    const int fq = lane >> 4;
    const int srow = lane >> 2;
    const int scol = (lane & 3) * 8;

    f32x4 acc[4][4] = {};

    for (int kt = 0; kt < 16; ++kt) {
        const int k0 = kt << 5;
        __syncthreads();
        #pragma unroll
        for (int s = 0; s < 2; ++s) {
            const int seg = wid * 2 + s;
            const unsigned short* gA = A + (size_t)(row0 + seg * 16 + srow) * 512 + k0 + scol;
            __builtin_amdgcn_global_load_lds(
                (const __attribute__((address_space(1))) void*)gA,
                (__attribute__((address_space(3))) void*)(sA + seg * 512), 16, 0, 0);
            const unsigned short* gB = Bt + (size_t)(col0 + seg * 16 + srow) * 512 + k0 + scol;
            __builtin_amdgcn_global_load_lds(
                (const __attribute__((address_space(1))) void*)gB,
                (__attribute__((address_space(3))) void*)(sB + seg * 512), 16, 0, 0);
        }
        __syncthreads();

        bf16x8 av[4], bfrag[4];
        #pragma unroll
        for (int m = 0; m < 4; ++m)
            av[m] = *(const bf16x8*)(sA + (wr + m * 16 + fr) * 32 + fq * 8);
        #pragma unroll
        for (int n = 0; n < 4; ++n)
            bfrag[n] = *(const bf16x8*)(sB + (wc + n * 16 + fr) * 32 + fq * 8);
        #pragma unroll
        for (int m = 0; m < 4; ++m)
            #pragma unroll
            for (int n = 0; n < 4; ++n)
                acc[m][n] = __builtin_amdgcn_mfma_f32_16x16x32_bf16(av[m], bfrag[n], acc[m][n], 0, 0, 0);
    }

    const int sec = col0 >> 9;                  // block-uniform
    const int cs0 = (col0 & 511) + wc;          // col within section (+ n*16 + fr)

    if (sec == 0) {
        // ---- keys: bf16 out + column stats over this wave's 64 rows ----
        const int pb = by * 2 + (wr >> 6);      // 128 partial rows
        #pragma unroll
        for (int n = 0; n < 4; ++n) {
            const int col = cs0 + n * 16 + fr;
            const float bv = bias[col];
            float vv[4][4], mx = -1e30f;
            #pragma unroll
            for (int m = 0; m < 4; ++m)
                #pragma unroll
                for (int r = 0; r < 4; ++r) {
                    float x = bf2f(f2bf(acc[m][n][r] + bv));
                    vv[m][r] = x; mx = fmaxf(mx, x);
                }
            mx = fmaxf(mx, __shfl_xor(mx, 16));
            mx = fmaxf(mx, __shfl_xor(mx, 32));
            float s = 0.f;
            #pragma unroll
            for (int m = 0; m < 4; ++m)
                #pragma unroll
                for (int r = 0; r < 4; ++r) {
                    s += __expf(vv[m][r] - mx);
                    kbf[(size_t)(row0 + wr + m * 16 + fq * 4 + r) * 512 + col] = f2bf(vv[m][r]);
                }
            s += __shfl_xor(s, 16);
            s += __shfl_xor(s, 32);
            if (lane < 16) { pmax[pb * 512 + col] = mx; psum[pb * 512 + col] = s; }
        }
    } else if (sec == 1) {
        // ---- queries: full row softmax over 64 head-channels (wave-local) ----
        #pragma unroll
        for (int m = 0; m < 4; ++m)
            #pragma unroll
            for (int r = 0; r < 4; ++r) {
                float e[4], mx = -1e30f;
                #pragma unroll
                for (int n = 0; n < 4; ++n) {
                    float x = bf2f(f2bf(acc[m][n][r] + bias[512 + cs0 + n * 16 + fr]));
                    e[n] = x; mx = fmaxf(mx, x);
                }
                mx = fmaxf(mx, __shfl_xor(mx, 1));
                mx = fmaxf(mx, __shfl_xor(mx, 2));
                mx = fmaxf(mx, __shfl_xor(mx, 4));
                mx = fmaxf(mx, __shfl_xor(mx, 8));
                float s = 0.f;
                #pragma unroll
                for (int n = 0; n < 4; ++n) { e[n] = __expf(e[n] - mx); s += e[n]; }
                s += __shfl_xor(s, 1);
                s += __shfl_xor(s, 2);
                s += __shfl_xor(s, 4);
                s += __shfl_xor(s, 8);
                const float rs = 1.f / s;
                const int row = row0 + wr + m * 16 + fq * 4 + r;
                #pragma unroll
                for (int n = 0; n < 4; ++n)
                    qsm[(size_t)row * 512 + cs0 + n * 16 + fr] = f2bf(e[n] * rs);
            }
    } else {
        // ---- values: straight bf16 ----
        #pragma unroll
        for (int n = 0; n < 4; ++n) {
            const int col = cs0 + n * 16 + fr;
            const float bv = bias[1024 + col];
            #pragma unroll
            for (int m = 0; m < 4; ++m)
                #pragma unroll
                for (int r = 0; r < 4; ++r)
                    vbf[(size_t)(row0 + wr + m * 16 + fq * 4 + r) * 512 + col] = f2bf(acc[m][n][r] + bv);
        }
    }
}

// ---------------- key softmax finalize ----------------

__global__ void colms_final_k(const float* __restrict__ pmax, const float* __restrict__ psum,
                              float* __restrict__ cmax, float* __restrict__ crcp) {
    int c = blockIdx.x * 256 + threadIdx.x;   // 512 total
    float m = -1e30f;
    for (int b = 0; b < 128; ++b) m = fmaxf(m, pmax[b * 512 + c]);
    float s = 0.f;
    for (int b = 0; b < 128; ++b) s += psum[b * 512 + c] * __expf(pmax[b * 512 + c] - m);
    cmax[c] = m;
    crcp[c] = 1.f / s;
}

__global__ void ksm_k(const uint4* __restrict__ kbf, const float* __restrict__ cmax,
                      const float* __restrict__ crcp, uint4* __restrict__ ksm) {
    int idx = blockIdx.x * 256 + threadIdx.x;   // 524288 (8 bf16 each)
    int c8 = (idx & 63) * 8;
    uint4 raw = kbf[idx];
    const unsigned short* in = (const unsigned short*)&raw;
    unsigned short out[8];
    #pragma unroll
    for (int e = 0; e < 8; ++e)
        out[e] = f2bf(__expf(bf2f(in[e]) - cmax[c8 + e]) * crcp[c8 + e]);
    ksm[idx] = *(const uint4*)out;
}

// ---------------- context = k_sm^T @ v per head via MFMA on LDS-transposed tiles ----------------
__global__ __launch_bounds__(256) void context_partial_k(
    const unsigned short* __restrict__ ksm, const unsigned short* __restrict__ vbf,
    float* __restrict__ pctx)
{
    const int ch = blockIdx.x;   // 32 chunks x 256 rows
    const int h  = blockIdx.y;   // 8 heads
    const int tid = threadIdx.x, w = tid >> 6, lane = tid & 63;
    const int fr = lane & 15, fq = lane >> 4;
    __shared__ unsigned short tr[4][2][4096];   // [wave][k/v][64 kchan * 64 tok]
    char* kt = (char*)&tr[w][0][0];
    char* vt = (char*)&tr[w][1][0];
    const int nbase = ch * 256 + w * 64;

    #pragma unroll
    for (int j = 0; j < 8; ++j) {
        bf16x8 kv = *(const bf16x8*)(ksm + (size_t)(nbase + lane) * 512 + h * 64 + j * 8);
        bf16x8 vv = *(const bf16x8*)(vbf + (size_t)(nbase + lane) * 512 + h * 64 + j * 8);
        #pragma unroll
        for (int e = 0; e < 8; ++e) {
            int k = j * 8 + e;
            int byte = (k * 128 + lane * 2) ^ (e << 4);   // k&7 == e
            *(unsigned short*)(kt + byte) = ((const unsigned short*)&kv)[e];
            *(unsigned short*)(vt + byte) = ((const unsigned short*)&vv)[e];
        }
    }
    asm volatile("s_waitcnt lgkmcnt(0)" ::: "memory");
    __builtin_amdgcn_sched_barrier(0);

    f32x4 acc[4][4] = {};
    #pragma unroll
    for (int ks = 0; ks < 2; ++ks) {
        bf16x8 a[4], b[4];
        #pragma unroll
        for (int mf = 0; mf < 4; ++mf) {
            int row  = mf * 16 + fr;
            int byte = (row * 128 + (ks * 4 + fq) * 16) ^ ((row & 7) << 4);
            a[mf] = *(const bf16x8*)(kt + byte);
            b[mf] = *(const bf16x8*)(vt + byte);
        }
        #pragma unroll
        for (int mf = 0; mf < 4; ++mf)
            #pragma unroll
            for (int nf = 0; nf < 4; ++nf)
                acc[mf][nf] = __builtin_amdgcn_mfma_f32_16x16x32_bf16(a[mf], b[nf], acc[mf][nf], 0, 0, 0);
    }

    float* out = pctx + (size_t)((ch * 4 + w) * 8 + h) * 4096;
    #pragma unroll
    for (int mf = 0; mf < 4; ++mf)
        #pragma unroll
        for (int nf = 0; nf < 4; ++nf)
            #pragma unroll
            for (int r = 0; r < 4; ++r)
                out[(mf * 16 + fq * 4 + r) * 64 + nf * 16 + fr] = acc[mf][nf][r];
}
__global__ void context_reduce_k(const float* __restrict__ pctx, float* __restrict__ ctx) {
    int idx = blockIdx.x * 256 + threadIdx.x;   // 8*4096 = 32768
    int h = idx >> 12, e = idx & 4095;
    float s = 0.f;
    for (int p = 0; p < 128; ++p) s += pctx[(size_t)(p * 8 + h) * 4096 + e];
    ctx[idx] = s;
}

// ---------------- Mt[o][h*64+k] = sum_j ctx[h][k][j] * Wr[h*64+j][o]  (bf16) ----------------
__global__ void mt_k(const float* __restrict__ ctx, const float* __restrict__ Wr,
                     unsigned short* __restrict__ Mt) {
    int idx = blockIdx.x * 256 + threadIdx.x;   // 512*512
    int o = idx >> 9, hk = idx & 511;
    int h = hk >> 6, k = hk & 63;
    float s = 0.f;
    for (int j = 0; j < 64; ++j)
        s += ctx[h * 4096 + k * 64 + j] * Wr[(size_t)(h * 64 + j) * 512 + o];
    Mt[(size_t)o * 512 + hk] = f2bf(s);
}

// ---------------- attention GEMM (nt stores): C = A @ Bt^T + bias ----------------
__global__ __launch_bounds__(256) void attn_gemm_k(
    const unsigned short* __restrict__ A, const unsigned short* __restrict__ Bt,
    float* __restrict__ C, const float* __restrict__ bias)
{
    __shared__ unsigned short sA[128 * 32];
    __shared__ unsigned short sB[128 * 32];
    const int tid  = threadIdx.x;
    const int wid  = tid >> 6;
    const int lane = tid & 63;
    const int col0 = blockIdx.x * 128;
    const int row0 = blockIdx.y * 128;
    const int wr = (wid >> 1) * 64;
    const int wc = (wid & 1) * 64;
    const int fr = lane & 15;
    const int fq = lane >> 4;
    const int srow = lane >> 2;
    const int scol = (lane & 3) * 8;

    f32x4 acc[4][4] = {};

    for (int kt = 0; kt < 16; ++kt) {
        const int k0 = kt << 5;
        __syncthreads();
        #pragma unroll
        for (int s = 0; s < 2; ++s) {
            const int seg = wid * 2 + s;
            const unsigned short* gA = A + (size_t)(row0 + seg * 16 + srow) * 512 + k0 + scol;
            __builtin_amdgcn_global_load_lds(
                (const __attribute__((address_space(1))) void*)gA,
                (__attribute__((address_space(3))) void*)(sA + seg * 512), 16, 0, 0);
            const unsigned short* gB = Bt + (size_t)(col0 + seg * 16 + srow) * 512 + k0 + scol;
            __builtin_amdgcn_global_load_lds(
                (const __attribute__((address_space(1))) void*)gB,
                (__attribute__((address_space(3))) void*)(sB + seg * 512), 16, 0, 0);
        }
        __syncthreads();

        bf16x8 av[4], bfrag[4];
        #pragma unroll
        for (int m = 0; m < 4; ++m)
            av[m] = *(const bf16x8*)(sA + (wr + m * 16 + fr) * 32 + fq * 8);
        #pragma unroll
        for (int n = 0; n < 4; ++n)
            bfrag[n] = *(const bf16x8*)(sB + (wc + n * 16 + fr) * 32 + fq * 8);
        #pragma unroll
        for (int m = 0; m < 4; ++m)
            #pragma unroll
            for (int n = 0; n < 4; ++n)
                acc[m][n] = __builtin_amdgcn_mfma_f32_16x16x32_bf16(av[m], bfrag[n], acc[m][n], 0, 0, 0);
    }

    #pragma unroll
    for (int n = 0; n < 4; ++n) {
        const int col = col0 + wc + n * 16 + fr;
        const float bval = bias[col];
        #pragma unroll
        for (int m = 0; m < 4; ++m) {
            #pragma unroll
            for (int r = 0; r < 4; ++r) {
                const int row = row0 + wr + m * 16 + fq * 4 + r;
                __builtin_nontemporal_store(acc[m][n][r] + bval, &C[(size_t)row * 512 + col]);
            }
        }
    }
}

// ---------------- scores GEMM: m97 128x128, XCD swizzle, nontemporal C ----------------
// C[8192,8192] = 0.125 * qsm @ ksm^T
__global__ __launch_bounds__(256) void scores_nt_k(
    const unsigned short* __restrict__ A, const unsigned short* __restrict__ B,
    float* __restrict__ C)
{
    __shared__ unsigned short sA[128 * 32];
    __shared__ unsigned short sB[128 * 32];
    const int tid  = threadIdx.x;
    const int wid  = tid >> 6;
    const int lane = tid & 63;
    const int wr = (wid >> 1) * 64;
    const int wc = (wid & 1) * 64;
    const int fr = lane & 15;
    const int fq = lane >> 4;
    const int srow = lane >> 2;
    const int scol = (lane & 3) * 8;

    // bijective XCD swizzle (4096 % 8 == 0) + GM=8 row grouping for L2
    int g = blockIdx.x;
    g = (g & 7) * 512 + (g >> 3);
    const int by = (g & 7) + ((g >> 9) << 3);
    const int bx = (g >> 3) & 63;
    const int row0 = by * 128, col0 = bx * 128;

    f32x4 acc[4][4] = {};

    for (int kt = 0; kt < 16; ++kt) {
        const int k0 = kt << 5;
        __syncthreads();
        #pragma unroll
        for (int s = 0; s < 2; ++s) {
            const int seg = wid * 2 + s;
            const unsigned short* gA = A + (size_t)(row0 + seg * 16 + srow) * 512 + k0 + scol;
            __builtin_amdgcn_global_load_lds(
                (const __attribute__((address_space(1))) void*)gA,
                (__attribute__((address_space(3))) void*)(sA + seg * 512), 16, 0, 0);
            const unsigned short* gB = B + (size_t)(col0 + seg * 16 + srow) * 512 + k0 + scol;
            __builtin_amdgcn_global_load_lds(
                (const __attribute__((address_space(1))) void*)gB,
                (__attribute__((address_space(3))) void*)(sB + seg * 512), 16, 0, 0);
        }
        __syncthreads();

        bf16x8 av[4], bfrag[4];
        #pragma unroll
        for (int m = 0; m < 4; ++m)
            av[m] = *(const bf16x8*)(sA + (wr + m * 16 + fr) * 32 + fq * 8);
        #pragma unroll
        for (int n = 0; n < 4; ++n)
            bfrag[n] = *(const bf16x8*)(sB + (wc + n * 16 + fr) * 32 + fq * 8);
        #pragma unroll
        for (int m = 0; m < 4; ++m)
            #pragma unroll
            for (int n = 0; n < 4; ++n)
                acc[m][n] = __builtin_amdgcn_mfma_f32_16x16x32_bf16(av[m], bfrag[n], acc[m][n], 0, 0, 0);
    }

    #pragma unroll
    for (int n = 0; n < 4; ++n) {
        const int col = col0 + wc + n * 16 + fr;
        #pragma unroll
        for (int m = 0; m < 4; ++m) {
            #pragma unroll
            for (int r = 0; r < 4; ++r) {
                const int row = row0 + wr + m * 16 + fq * 4 + r;
                __builtin_nontemporal_store(acc[m][n][r] * 0.125f, &C[(size_t)row * SC_N + col]);
            }
        }
    }
}

// ---------------- launch ----------------
extern "C" void kernel_launch(void* const* d_in, const int* in_sizes, int n_in,
                              void* d_out, int out_size, void* d_ws, size_t ws_size,
                              hipStream_t stream) {
    const float* input = (const float*)d_in[0];
    const float* Wk = (const float*)d_in[1];
    const float* bk = (const float*)d_in[2];
    const float* Wq = (const float*)d_in[3];
    const float* bq = (const float*)d_in[4];
    const float* Wv = (const float*)d_in[5];
    const float* bv = (const float*)d_in[6];
    const float* Wr = (const float*)d_in[7];
    const float* br = (const float*)d_in[8];

    char* ws = (char*)d_ws;
    unsigned short* inp_bf = (unsigned short*)ws;  ws += (size_t)NT * CD * 2;
    unsigned short* Wt     = (unsigned short*)ws;  ws += (size_t)1536 * 512 * 2;
    float* biaskqv         = (float*)ws;           ws += 1536 * 4;
    unsigned short* kbf    = (unsigned short*)ws;  ws += (size_t)NT * CD * 2;
    unsigned short* qsm    = (unsigned short*)ws;  ws += (size_t)NT * CD * 2;
    unsigned short* vbf    = (unsigned short*)ws;  ws += (size_t)NT * CD * 2;
    unsigned short* ksm    = (unsigned short*)ws;  ws += (size_t)NT * CD * 2;
    float* pmax            = (float*)ws;           ws += 128 * 512 * 4;
    float* psum            = (float*)ws;           ws += 128 * 512 * 4;
    float* cmax            = (float*)ws;           ws += 512 * 4;
    float* crcp            = (float*)ws;           ws += 512 * 4;
    float* pctx            = (float*)ws;           ws += (size_t)128 * 8 * 4096 * 4;
    float* ctx             = (float*)ws;           ws += (size_t)8 * 4096 * 4;
    unsigned short* Mt     = (unsigned short*)ws;  ws += (size_t)512 * 512 * 2;

    float* attn_out   = (float*)d_out;
    float* scores_out = (float*)d_out + (size_t)NT * CD;

    cvt_input_k<<<4096, 256, 0, stream>>>((const float4*)input, inp_bf);
    prep_w_k<<<3072, 256, 0, stream>>>(Wk, Wq, Wv, bk, bq, bv, Wt, biaskqv);

    kqv_gemm_k<<<dim3(12, 64), 256, 0, stream>>>(inp_bf, Wt, biaskqv,
                                                 kbf, qsm, vbf, pmax, psum);

    colms_final_k<<<2, 256, 0, stream>>>(pmax, psum, cmax, crcp);
    ksm_k<<<2048, 256, 0, stream>>>((const uint4*)kbf, cmax, crcp, (uint4*)ksm);

    context_partial_k<<<dim3(32, 8), 256, 0, stream>>>(ksm, vbf, pctx);
    context_reduce_k<<<128, 256, 0, stream>>>(pctx, ctx);
    mt_k<<<1024, 256, 0, stream>>>(ctx, Wr, Mt);

    attn_gemm_k<<<dim3(4, 64), 256, 0, stream>>>(qsm, Mt, attn_out, br);
    scores_nt_k<<<4096, 256, 0, stream>>>(qsm, ksm, scores_out);
}

// Round 6
// 220.876 us; speedup vs baseline: 1.2681x; 1.0594x over previous
//
#include <hip/hip_runtime.h>

#define NT 8192      // tokens
#define CD 512       // C_K = C_V = 512
#define NH 8         // heads
#define SC_N 8192

using f32x4  = __attribute__((ext_vector_type(4))) float;
using bf16x8 = __attribute__((ext_vector_type(8))) __bf16;

__device__ __forceinline__ unsigned short f2bf(float x) {
    union { float f; unsigned u; } c; c.f = x;
    unsigned r = c.u + 0x7fffu + ((c.u >> 16) & 1u);
    return (unsigned short)(r >> 16);
}
__device__ __forceinline__ float bf2f(unsigned short b) {
    union { float f; unsigned u; } c; c.u = ((unsigned)b) << 16;
    return c.f;
}

// ---------------- merged prep: input cvt (blocks 0..4095) + W transpose (4096..7167) ----------------
__global__ void prep_k(const float4* __restrict__ in, unsigned short* __restrict__ out,
                       const float* __restrict__ Wk, const float* __restrict__ Wq,
                       const float* __restrict__ Wv, const float* __restrict__ bk,
                       const float* __restrict__ bq, const float* __restrict__ bv,
                       unsigned short* __restrict__ Wt, float* __restrict__ biaskqv) {
    int b = blockIdx.x;
    if (b < 4096) {
        int i = b * 256 + threadIdx.x;
        float4 v = in[i];
        out[i*4+0] = f2bf(v.x);
        out[i*4+1] = f2bf(v.y);
        out[i*4+2] = f2bf(v.z);
        out[i*4+3] = f2bf(v.w);
    } else {
        int idx = (b - 4096) * 256 + threadIdx.x;   // 1536*512
        int c = idx >> 9, k = idx & 511;
        int sec = c >> 9, cc = c & 511;
        const float* W = (sec == 0) ? Wk : ((sec == 1) ? Wq : Wv);
        Wt[idx] = f2bf(W[k * 512 + cc]);
        if (idx < 1536) {
            const float* bb = (idx < 512) ? bk : ((idx < 1024) ? bq : bv);
            biaskqv[idx] = bb[idx & 511];
        }
    }
}

// ---------------- KQV GEMM with fused epilogues ----------------
__global__ __launch_bounds__(256) void kqv_gemm_k(
    const unsigned short* __restrict__ A, const unsigned short* __restrict__ Bt,
    const float* __restrict__ bias,
    unsigned short* __restrict__ kbf, unsigned short* __restrict__ qsm,
    unsigned short* __restrict__ vbf,
    float* __restrict__ pmax, float* __restrict__ psum)
{
    __shared__ unsigned short sA[128 * 32];
    __shared__ unsigned short sB[128 * 32];
    const int tid  = threadIdx.x;
    const int wid  = tid >> 6;
    const int lane = tid & 63;
    const int col0 = blockIdx.x * 128;     // 0..1535
    const int row0 = blockIdx.y * 128;
    const int by   = blockIdx.y;
    const int wr = (wid >> 1) * 64;
    const int wc = (wid & 1) * 64;
    const int fr = lane & 15;
    const int fq = lane >> 4;
    const int srow = lane >> 2;
    const int scol = (lane & 3) * 8;

    f32x4 acc[4][4] = {};

    for (int kt = 0; kt < 16; ++kt) {
        const int k0 = kt << 5;
        __syncthreads();
        #pragma unroll
        for (int s = 0; s < 2; ++s) {
            const int seg = wid * 2 + s;
            const unsigned short* gA = A + (size_t)(row0 + seg * 16 + srow) * 512 + k0 + scol;
            __builtin_amdgcn_global_load_lds(
                (const __attribute__((address_space(1))) void*)gA,
                (__attribute__((address_space(3))) void*)(sA + seg * 512), 16, 0, 0);
            const unsigned short* gB = Bt + (size_t)(col0 + seg * 16 + srow) * 512 + k0 + scol;
            __builtin_amdgcn_global_load_lds(
                (const __attribute__((address_space(1))) void*)gB,
                (__attribute__((address_space(3))) void*)(sB + seg * 512), 16, 0, 0);
        }
        __syncthreads();

        bf16x8 av[4], bfrag[4];
        #pragma unroll
        for (int m = 0; m < 4; ++m)
            av[m] = *(const bf16x8*)(sA + (wr + m * 16 + fr) * 32 + fq * 8);
        #pragma unroll
        for (int n = 0; n < 4; ++n)
            bfrag[n] = *(const bf16x8*)(sB + (wc + n * 16 + fr) * 32 + fq * 8);
        #pragma unroll
        for (int m = 0; m < 4; ++m)
            #pragma unroll
            for (int n = 0; n < 4; ++n)
                acc[m][n] = __builtin_amdgcn_mfma_f32_16x16x32_bf16(av[m], bfrag[n], acc[m][n], 0, 0, 0);
    }

    const int sec = col0 >> 9;
    const int cs0 = (col0 & 511) + wc;

    if (sec == 0) {
        const int pb = by * 2 + (wr >> 6);      // 128 partial rows
        #pragma unroll
        for (int n = 0; n < 4; ++n) {
            const int col = cs0 + n * 16 + fr;
            const float bv = bias[col];
            float vv[4][4], mx = -1e30f;
            #pragma unroll
            for (int m = 0; m < 4; ++m)
                #pragma unroll
                for (int r = 0; r < 4; ++r) {
                    float x = bf2f(f2bf(acc[m][n][r] + bv));
                    vv[m][r] = x; mx = fmaxf(mx, x);
                }
            mx = fmaxf(mx, __shfl_xor(mx, 16));
            mx = fmaxf(mx, __shfl_xor(mx, 32));
            float s = 0.f;
            #pragma unroll
            for (int m = 0; m < 4; ++m)
                #pragma unroll
                for (int r = 0; r < 4; ++r) {
                    s += __expf(vv[m][r] - mx);
                    kbf[(size_t)(row0 + wr + m * 16 + fq * 4 + r) * 512 + col] = f2bf(vv[m][r]);
                }
            s += __shfl_xor(s, 16);
            s += __shfl_xor(s, 32);
            if (lane < 16) { pmax[pb * 512 + col] = mx; psum[pb * 512 + col] = s; }
        }
    } else if (sec == 1) {
        #pragma unroll
        for (int m = 0; m < 4; ++m)
            #pragma unroll
            for (int r = 0; r < 4; ++r) {
                float e[4], mx = -1e30f;
                #pragma unroll
                for (int n = 0; n < 4; ++n) {
                    float x = bf2f(f2bf(acc[m][n][r] + bias[512 + cs0 + n * 16 + fr]));
                    e[n] = x; mx = fmaxf(mx, x);
                }
                mx = fmaxf(mx, __shfl_xor(mx, 1));
                mx = fmaxf(mx, __shfl_xor(mx, 2));
                mx = fmaxf(mx, __shfl_xor(mx, 4));
                mx = fmaxf(mx, __shfl_xor(mx, 8));
                float s = 0.f;
                #pragma unroll
                for (int n = 0; n < 4; ++n) { e[n] = __expf(e[n] - mx); s += e[n]; }
                s += __shfl_xor(s, 1);
                s += __shfl_xor(s, 2);
                s += __shfl_xor(s, 4);
                s += __shfl_xor(s, 8);
                const float rs = 1.f / s;
                const int row = row0 + wr + m * 16 + fq * 4 + r;
                #pragma unroll
                for (int n = 0; n < 4; ++n)
                    qsm[(size_t)row * 512 + cs0 + n * 16 + fr] = f2bf(e[n] * rs);
            }
    } else {
        #pragma unroll
        for (int n = 0; n < 4; ++n) {
            const int col = cs0 + n * 16 + fr;
            const float bv = bias[1024 + col];
            #pragma unroll
            for (int m = 0; m < 4; ++m)
                #pragma unroll
                for (int r = 0; r < 4; ++r)
                    vbf[(size_t)(row0 + wr + m * 16 + fq * 4 + r) * 512 + col] = f2bf(acc[m][n][r] + bv);
        }
    }
}

// ---------------- key softmax finalize ----------------

__global__ void colms_final_k(const float* __restrict__ pmax, const float* __restrict__ psum,
                              float* __restrict__ cmax, float* __restrict__ crcp) {
    int c = blockIdx.x * 256 + threadIdx.x;   // 512 total
    float m = -1e30f;
    for (int b = 0; b < 128; ++b) m = fmaxf(m, pmax[b * 512 + c]);
    float s = 0.f;
    for (int b = 0; b < 128; ++b) s += psum[b * 512 + c] * __expf(pmax[b * 512 + c] - m);
    cmax[c] = m;
    crcp[c] = 1.f / s;
}

__global__ void ksm_k(const uint4* __restrict__ kbf, const float* __restrict__ cmax,
                      const float* __restrict__ crcp, uint4* __restrict__ ksm) {
    int idx = blockIdx.x * 256 + threadIdx.x;   // 524288 (8 bf16 each)
    int c8 = (idx & 63) * 8;
    uint4 raw = kbf[idx];
    const unsigned short* in = (const unsigned short*)&raw;
    unsigned short out[8];
    #pragma unroll
    for (int e = 0; e < 8; ++e)
        out[e] = f2bf(__expf(bf2f(in[e]) - cmax[c8 + e]) * crcp[c8 + e]);
    ksm[idx] = *(const uint4*)out;
}

// ---------------- context = k_sm^T @ v per head via MFMA + cross-wave LDS reduce ----------------
// Block: 256 tokens x 1 head; wave w owns 64 tokens. After MFMA, all 4 waves'
// 64x64 accs are summed through LDS (reusing the 64KB tr buffer) -> 32 partials.
__global__ __launch_bounds__(256) void context_partial_k(
    const unsigned short* __restrict__ ksm, const unsigned short* __restrict__ vbf,
    float* __restrict__ pctx)
{
    const int ch = blockIdx.x;   // 32 chunks x 256 rows
    const int h  = blockIdx.y;   // 8 heads
    const int tid = threadIdx.x, w = tid >> 6, lane = tid & 63;
    const int fr = lane & 15, fq = lane >> 4;
    __shared__ unsigned short tr[4][2][4096];   // 64 KiB; reused as fp32 scratch later
    char* kt = (char*)&tr[w][0][0];
    char* vt = (char*)&tr[w][1][0];
    const int nbase = ch * 256 + w * 64;

    #pragma unroll
    for (int j = 0; j < 8; ++j) {
        bf16x8 kv = *(const bf16x8*)(ksm + (size_t)(nbase + lane) * 512 + h * 64 + j * 8);
        bf16x8 vv = *(const bf16x8*)(vbf + (size_t)(nbase + lane) * 512 + h * 64 + j * 8);
        #pragma unroll
        for (int e = 0; e < 8; ++e) {
            int k = j * 8 + e;
            int byte = (k * 128 + lane * 2) ^ (e << 4);   // k&7 == e
            *(unsigned short*)(kt + byte) = ((const unsigned short*)&kv)[e];
            *(unsigned short*)(vt + byte) = ((const unsigned short*)&vv)[e];
        }
    }
    asm volatile("s_waitcnt lgkmcnt(0)" ::: "memory");
    __builtin_amdgcn_sched_barrier(0);

    f32x4 acc[4][4] = {};
    #pragma unroll
    for (int ks = 0; ks < 2; ++ks) {
        bf16x8 a[4], b[4];
        #pragma unroll
        for (int mf = 0; mf < 4; ++mf) {
            int row  = mf * 16 + fr;
            int byte = (row * 128 + (ks * 4 + fq) * 16) ^ ((row & 7) << 4);
            a[mf] = *(const bf16x8*)(kt + byte);
            b[mf] = *(const bf16x8*)(vt + byte);
        }
        #pragma unroll
        for (int mf = 0; mf < 4; ++mf)
            #pragma unroll
            for (int nf = 0; nf < 4; ++nf)
                acc[mf][nf] = __builtin_amdgcn_mfma_f32_16x16x32_bf16(a[mf], b[nf], acc[mf][nf], 0, 0, 0);
    }

    // cross-wave reduce: wave w writes its 64x64 acc into its own 16KB region
    // (same region as its tr tiles -- own reads already consumed), swizzled so
    // the per-instruction (fq-spread) write is 2-way bank aliased.
    float* red = (float*)&tr[w][0][0];   // 4096 floats
    #pragma unroll
    for (int mf = 0; mf < 4; ++mf)
        #pragma unroll
        for (int nf = 0; nf < 4; ++nf)
            #pragma unroll
            for (int r = 0; r < 4; ++r) {
                int lr = mf * 16 + fq * 4 + r;
                int lc = (nf * 16 + fr) ^ (((lr >> 2) & 1) << 4);
                red[lr * 64 + lc] = acc[mf][nf][r];
            }
    __syncthreads();
    const float* rbase = (const float*)&tr[0][0][0];
    float* out = pctx + (size_t)(ch * 8 + h) * 4096;
    #pragma unroll
    for (int it = 0; it < 16; ++it) {
        int e = it * 256 + tid;
        int lr = e >> 6;
        int ph = (lr * 64) + ((e & 63) ^ (((lr >> 2) & 1) << 4));
        float s = rbase[ph] + rbase[4096 + ph] + rbase[8192 + ph] + rbase[12288 + ph];
        out[e] = s;
    }
}
__global__ void context_reduce_k(const float* __restrict__ pctx, float* __restrict__ ctx) {
    int idx = blockIdx.x * 256 + threadIdx.x;   // 8*4096 = 32768
    int h = idx >> 12, e = idx & 4095;
    float s = 0.f;
    for (int p = 0; p < 32; ++p) s += pctx[(size_t)(p * 8 + h) * 4096 + e];
    ctx[idx] = s;
}

// ---------------- Mt[o][hk] = sum_j ctx[h][k][j] * Wr[h*64+j][o]  (coalesced) ----------------
// block b: hk = b>>1, o = (b&1)*256 + tid. ctx row is wave-uniform (scalar);
// Wr reads coalesced (1KB/wave-iter).
__global__ void mt_k(const float* __restrict__ ctx, const float* __restrict__ Wr,
                     unsigned short* __restrict__ Mt) {
    const int b = blockIdx.x;            // 1024
    const int hk = b >> 1;
    const int o  = (b & 1) * 256 + threadIdx.x;
    const int h = hk >> 6, k = hk & 63;
    const float* cr = ctx + h * 4096 + k * 64;
    const float* wp = Wr + (size_t)(h * 64) * 512 + o;
    float s = 0.f;
    #pragma unroll
    for (int j = 0; j < 64; ++j)
        s += cr[j] * wp[(size_t)j * 512];
    Mt[(size_t)o * 512 + hk] = f2bf(s);
}

// ---------------- attention GEMM (nt stores): C = A @ Bt^T + bias ----------------
__global__ __launch_bounds__(256) void attn_gemm_k(
    const unsigned short* __restrict__ A, const unsigned short* __restrict__ Bt,
    float* __restrict__ C, const float* __restrict__ bias)
{
    __shared__ unsigned short sA[128 * 32];
    __shared__ unsigned short sB[128 * 32];
    const int tid  = threadIdx.x;
    const int wid  = tid >> 6;
    const int lane = tid & 63;
    const int col0 = blockIdx.x * 128;
    const int row0 = blockIdx.y * 128;
    const int wr = (wid >> 1) * 64;
    const int wc = (wid & 1) * 64;
    const int fr = lane & 15;
    const int fq = lane >> 4;
    const int srow = lane >> 2;
    const int scol = (lane & 3) * 8;

    f32x4 acc[4][4] = {};

    for (int kt = 0; kt < 16; ++kt) {
        const int k0 = kt << 5;
        __syncthreads();
        #pragma unroll
        for (int s = 0; s < 2; ++s) {
            const int seg = wid * 2 + s;
            const unsigned short* gA = A + (size_t)(row0 + seg * 16 + srow) * 512 + k0 + scol;
            __builtin_amdgcn_global_load_lds(
                (const __attribute__((address_space(1))) void*)gA,
                (__attribute__((address_space(3))) void*)(sA + seg * 512), 16, 0, 0);
            const unsigned short* gB = Bt + (size_t)(col0 + seg * 16 + srow) * 512 + k0 + scol;
            __builtin_amdgcn_global_load_lds(
                (const __attribute__((address_space(1))) void*)gB,
                (__attribute__((address_space(3))) void*)(sB + seg * 512), 16, 0, 0);
        }
        __syncthreads();

        bf16x8 av[4], bfrag[4];
        #pragma unroll
        for (int m = 0; m < 4; ++m)
            av[m] = *(const bf16x8*)(sA + (wr + m * 16 + fr) * 32 + fq * 8);
        #pragma unroll
        for (int n = 0; n < 4; ++n)
            bfrag[n] = *(const bf16x8*)(sB + (wc + n * 16 + fr) * 32 + fq * 8);
        #pragma unroll
        for (int m = 0; m < 4; ++m)
            #pragma unroll
            for (int n = 0; n < 4; ++n)
                acc[m][n] = __builtin_amdgcn_mfma_f32_16x16x32_bf16(av[m], bfrag[n], acc[m][n], 0, 0, 0);
    }

    #pragma unroll
    for (int n = 0; n < 4; ++n) {
        const int col = col0 + wc + n * 16 + fr;
        const float bval = bias[col];
        #pragma unroll
        for (int m = 0; m < 4; ++m) {
            #pragma unroll
            for (int r = 0; r < 4; ++r) {
                const int row = row0 + wr + m * 16 + fq * 4 + r;
                __builtin_nontemporal_store(acc[m][n][r] + bval, &C[(size_t)row * 512 + col]);
            }
        }
    }
}

// ---------------- scores GEMM: m97 128x128, XCD swizzle, nontemporal C ----------------
__global__ __launch_bounds__(256) void scores_nt_k(
    const unsigned short* __restrict__ A, const unsigned short* __restrict__ B,
    float* __restrict__ C)
{
    __shared__ unsigned short sA[128 * 32];
    __shared__ unsigned short sB[128 * 32];
    const int tid  = threadIdx.x;
    const int wid  = tid >> 6;
    const int lane = tid & 63;
    const int wr = (wid >> 1) * 64;
    const int wc = (wid & 1) * 64;
    const int fr = lane & 15;
    const int fq = lane >> 4;
    const int srow = lane >> 2;
    const int scol = (lane & 3) * 8;

    int g = blockIdx.x;
    g = (g & 7) * 512 + (g >> 3);
    const int by = (g & 7) + ((g >> 9) << 3);
    const int bx = (g >> 3) & 63;
    const int row0 = by * 128, col0 = bx * 128;

    f32x4 acc[4][4] = {};

    for (int kt = 0; kt < 16; ++kt) {
        const int k0 = kt << 5;
        __syncthreads();
        #pragma unroll
        for (int s = 0; s < 2; ++s) {
            const int seg = wid * 2 + s;
            const unsigned short* gA = A + (size_t)(row0 + seg * 16 + srow) * 512 + k0 + scol;
            __builtin_amdgcn_global_load_lds(
                (const __attribute__((address_space(1))) void*)gA,
                (__attribute__((address_space(3))) void*)(sA + seg * 512), 16, 0, 0);
            const unsigned short* gB = B + (size_t)(col0 + seg * 16 + srow) * 512 + k0 + scol;
            __builtin_amdgcn_global_load_lds(
                (const __attribute__((address_space(1))) void*)gB,
                (__attribute__((address_space(3))) void*)(sB + seg * 512), 16, 0, 0);
        }
        __syncthreads();

        bf16x8 av[4], bfrag[4];
        #pragma unroll
        for (int m = 0; m < 4; ++m)
            av[m] = *(const bf16x8*)(sA + (wr + m * 16 + fr) * 32 + fq * 8);
        #pragma unroll
        for (int n = 0; n < 4; ++n)
            bfrag[n] = *(const bf16x8*)(sB + (wc + n * 16 + fr) * 32 + fq * 8);
        #pragma unroll
        for (int m = 0; m < 4; ++m)
            #pragma unroll
            for (int n = 0; n < 4; ++n)
                acc[m][n] = __builtin_amdgcn_mfma_f32_16x16x32_bf16(av[m], bfrag[n], acc[m][n], 0, 0, 0);
    }

    #pragma unroll
    for (int n = 0; n < 4; ++n) {
        const int col = col0 + wc + n * 16 + fr;
        #pragma unroll
        for (int m = 0; m < 4; ++m) {
            #pragma unroll
            for (int r = 0; r < 4; ++r) {
                const int row = row0 + wr + m * 16 + fq * 4 + r;
                __builtin_nontemporal_store(acc[m][n][r] * 0.125f, &C[(size_t)row * SC_N + col]);
            }
        }
    }
}

// ---------------- launch ----------------
extern "C" void kernel_launch(void* const* d_in, const int* in_sizes, int n_in,
                              void* d_out, int out_size, void* d_ws, size_t ws_size,
                              hipStream_t stream) {
    const float* input = (const float*)d_in[0];
    const float* Wk = (const float*)d_in[1];
    const float* bk = (const float*)d_in[2];
    const float* Wq = (const float*)d_in[3];
    const float* bq = (const float*)d_in[4];
    const float* Wv = (const float*)d_in[5];
    const float* bv = (const float*)d_in[6];
    const float* Wr = (const float*)d_in[7];
    const float* br = (const float*)d_in[8];

    char* ws = (char*)d_ws;
    unsigned short* inp_bf = (unsigned short*)ws;  ws += (size_t)NT * CD * 2;
    unsigned short* Wt     = (unsigned short*)ws;  ws += (size_t)1536 * 512 * 2;
    float* biaskqv         = (float*)ws;           ws += 1536 * 4;
    unsigned short* kbf    = (unsigned short*)ws;  ws += (size_t)NT * CD * 2;
    unsigned short* qsm    = (unsigned short*)ws;  ws += (size_t)NT * CD * 2;
    unsigned short* vbf    = (unsigned short*)ws;  ws += (size_t)NT * CD * 2;
    unsigned short* ksm    = (unsigned short*)ws;  ws += (size_t)NT * CD * 2;
    float* pmax            = (float*)ws;           ws += 128 * 512 * 4;
    float* psum            = (float*)ws;           ws += 128 * 512 * 4;
    float* cmax            = (float*)ws;           ws += 512 * 4;
    float* crcp            = (float*)ws;           ws += 512 * 4;
    float* pctx            = (float*)ws;           ws += (size_t)32 * 8 * 4096 * 4;
    float* ctx             = (float*)ws;           ws += (size_t)8 * 4096 * 4;
    unsigned short* Mt     = (unsigned short*)ws;  ws += (size_t)512 * 512 * 2;

    float* attn_out   = (float*)d_out;
    float* scores_out = (float*)d_out + (size_t)NT * CD;

    prep_k<<<7168, 256, 0, stream>>>((const float4*)input, inp_bf,
                                     Wk, Wq, Wv, bk, bq, bv, Wt, biaskqv);

    kqv_gemm_k<<<dim3(12, 64), 256, 0, stream>>>(inp_bf, Wt, biaskqv,
                                                 kbf, qsm, vbf, pmax, psum);

    colms_final_k<<<2, 256, 0, stream>>>(pmax, psum, cmax, crcp);
    ksm_k<<<2048, 256, 0, stream>>>((const uint4*)kbf, cmax, crcp, (uint4*)ksm);

    context_partial_k<<<dim3(32, 8), 256, 0, stream>>>(ksm, vbf, pctx);
    context_reduce_k<<<128, 256, 0, stream>>>(pctx, ctx);
    mt_k<<<1024, 256, 0, stream>>>(ctx, Wr, Mt);

    attn_gemm_k<<<dim3(4, 64), 256, 0, stream>>>(qsm, Mt, attn_out, br);
    scores_nt_k<<<4096, 256, 0, stream>>>(qsm, ksm, scores_out);
}

// Round 7
// 177.297 us; speedup vs baseline: 1.5798x; 1.2458x over previous
//
#include <hip/hip_runtime.h>

#define NT 8192      // tokens
#define CD 512       // C_K = C_V = 512
#define NH 8         // heads
#define SC_N 8192

using f32x4  = __attribute__((ext_vector_type(4))) float;
using bf16x8 = __attribute__((ext_vector_type(8))) __bf16;

__device__ __forceinline__ unsigned short f2bf(float x) {
    union { float f; unsigned u; } c; c.f = x;
    unsigned r = c.u + 0x7fffu + ((c.u >> 16) & 1u);
    return (unsigned short)(r >> 16);
}
__device__ __forceinline__ float bf2f(unsigned short b) {
    union { float f; unsigned u; } c; c.u = ((unsigned)b) << 16;
    return c.f;
}

// ---------------- merged prep: input cvt (blocks 0..4095) + W transpose (4096..7167) ----------------
__global__ void prep_k(const float4* __restrict__ in, unsigned short* __restrict__ out,
                       const float* __restrict__ Wk, const float* __restrict__ Wq,
                       const float* __restrict__ Wv, const float* __restrict__ bk,
                       const float* __restrict__ bq, const float* __restrict__ bv,
                       unsigned short* __restrict__ Wt, float* __restrict__ biaskqv) {
    int b = blockIdx.x;
    if (b < 4096) {
        int i = b * 256 + threadIdx.x;
        float4 v = in[i];
        out[i*4+0] = f2bf(v.x);
        out[i*4+1] = f2bf(v.y);
        out[i*4+2] = f2bf(v.z);
        out[i*4+3] = f2bf(v.w);
    } else {
        int idx = (b - 4096) * 256 + threadIdx.x;   // 1536*512
        int c = idx >> 9, k = idx & 511;
        int sec = c >> 9, cc = c & 511;
        const float* W = (sec == 0) ? Wk : ((sec == 1) ? Wq : Wv);
        Wt[idx] = f2bf(W[k * 512 + cc]);
        if (idx < 1536) {
            const float* bb = (idx < 512) ? bk : ((idx < 1024) ? bq : bv);
            biaskqv[idx] = bb[idx & 511];
        }
    }
}

// ---------------- KQV GEMM with fused epilogues ----------------
__global__ __launch_bounds__(256) void kqv_gemm_k(
    const unsigned short* __restrict__ A, const unsigned short* __restrict__ Bt,
    const float* __restrict__ bias,
    unsigned short* __restrict__ kbf, unsigned short* __restrict__ qsm,
    unsigned short* __restrict__ vbf,
    float* __restrict__ pmax, float* __restrict__ psum)
{
    __shared__ unsigned short sA[128 * 32];
    __shared__ unsigned short sB[128 * 32];
    const int tid  = threadIdx.x;
    const int wid  = tid >> 6;
    const int lane = tid & 63;
    const int col0 = blockIdx.x * 128;     // 0..1535
    const int row0 = blockIdx.y * 128;
    const int by   = blockIdx.y;
    const int wr = (wid >> 1) * 64;
    const int wc = (wid & 1) * 64;
    const int fr = lane & 15;
    const int fq = lane >> 4;
    const int srow = lane >> 2;
    const int scol = (lane & 3) * 8;

    f32x4 acc[4][4] = {};

    for (int kt = 0; kt < 16; ++kt) {
        const int k0 = kt << 5;
        __syncthreads();
        #pragma unroll
        for (int s = 0; s < 2; ++s) {
            const int seg = wid * 2 + s;
            const unsigned short* gA = A + (size_t)(row0 + seg * 16 + srow) * 512 + k0 + scol;
            __builtin_amdgcn_global_load_lds(
                (const __attribute__((address_space(1))) void*)gA,
                (__attribute__((address_space(3))) void*)(sA + seg * 512), 16, 0, 0);
            const unsigned short* gB = Bt + (size_t)(col0 + seg * 16 + srow) * 512 + k0 + scol;
            __builtin_amdgcn_global_load_lds(
                (const __attribute__((address_space(1))) void*)gB,
                (__attribute__((address_space(3))) void*)(sB + seg * 512), 16, 0, 0);
        }
        __syncthreads();

        bf16x8 av[4], bfrag[4];
        #pragma unroll
        for (int m = 0; m < 4; ++m)
            av[m] = *(const bf16x8*)(sA + (wr + m * 16 + fr) * 32 + fq * 8);
        #pragma unroll
        for (int n = 0; n < 4; ++n)
            bfrag[n] = *(const bf16x8*)(sB + (wc + n * 16 + fr) * 32 + fq * 8);
        #pragma unroll
        for (int m = 0; m < 4; ++m)
            #pragma unroll
            for (int n = 0; n < 4; ++n)
                acc[m][n] = __builtin_amdgcn_mfma_f32_16x16x32_bf16(av[m], bfrag[n], acc[m][n], 0, 0, 0);
    }

    const int sec = col0 >> 9;
    const int cs0 = (col0 & 511) + wc;

    if (sec == 0) {
        const int pb = by * 2 + (wr >> 6);      // 128 partial rows
        #pragma unroll
        for (int n = 0; n < 4; ++n) {
            const int col = cs0 + n * 16 + fr;
            const float bv = bias[col];
            float vv[4][4], mx = -1e30f;
            #pragma unroll
            for (int m = 0; m < 4; ++m)
                #pragma unroll
                for (int r = 0; r < 4; ++r) {
                    float x = bf2f(f2bf(acc[m][n][r] + bv));
                    vv[m][r] = x; mx = fmaxf(mx, x);
                }
            mx = fmaxf(mx, __shfl_xor(mx, 16));
            mx = fmaxf(mx, __shfl_xor(mx, 32));
            float s = 0.f;
            #pragma unroll
            for (int m = 0; m < 4; ++m)
                #pragma unroll
                for (int r = 0; r < 4; ++r) {
                    s += __expf(vv[m][r] - mx);
                    kbf[(size_t)(row0 + wr + m * 16 + fq * 4 + r) * 512 + col] = f2bf(vv[m][r]);
                }
            s += __shfl_xor(s, 16);
            s += __shfl_xor(s, 32);
            if (lane < 16) { pmax[pb * 512 + col] = mx; psum[pb * 512 + col] = s; }
        }
    } else if (sec == 1) {
        #pragma unroll
        for (int m = 0; m < 4; ++m)
            #pragma unroll
            for (int r = 0; r < 4; ++r) {
                float e[4], mx = -1e30f;
                #pragma unroll
                for (int n = 0; n < 4; ++n) {
                    float x = bf2f(f2bf(acc[m][n][r] + bias[512 + cs0 + n * 16 + fr]));
                    e[n] = x; mx = fmaxf(mx, x);
                }
                mx = fmaxf(mx, __shfl_xor(mx, 1));
                mx = fmaxf(mx, __shfl_xor(mx, 2));
                mx = fmaxf(mx, __shfl_xor(mx, 4));
                mx = fmaxf(mx, __shfl_xor(mx, 8));
                float s = 0.f;
                #pragma unroll
                for (int n = 0; n < 4; ++n) { e[n] = __expf(e[n] - mx); s += e[n]; }
                s += __shfl_xor(s, 1);
                s += __shfl_xor(s, 2);
                s += __shfl_xor(s, 4);
                s += __shfl_xor(s, 8);
                const float rs = 1.f / s;
                const int row = row0 + wr + m * 16 + fq * 4 + r;
                #pragma unroll
                for (int n = 0; n < 4; ++n)
                    qsm[(size_t)row * 512 + cs0 + n * 16 + fr] = f2bf(e[n] * rs);
            }
    } else {
        #pragma unroll
        for (int n = 0; n < 4; ++n) {
            const int col = cs0 + n * 16 + fr;
            const float bv = bias[1024 + col];
            #pragma unroll
            for (int m = 0; m < 4; ++m)
                #pragma unroll
                for (int r = 0; r < 4; ++r)
                    vbf[(size_t)(row0 + wr + m * 16 + fq * 4 + r) * 512 + col] = f2bf(acc[m][n][r] + bv);
        }
    }
}

// ---------------- ksmctx: colms_final + ksm + context_partial fused ----------------
// Block (ch,h): derives cmax/crcp for its 64 cols from pmax/psum, computes ksm
// (bf16) in-register while staging transposed K/V tiles, writes ksm for the
// scores GEMM, MFMAs k_sm^T @ v, cross-wave-reduces -> pctx[ch][h].
__global__ __launch_bounds__(256) void ksmctx_k(
    const unsigned short* __restrict__ kbf, const unsigned short* __restrict__ vbf,
    const float* __restrict__ pmax, const float* __restrict__ psum,
    unsigned short* __restrict__ ksm, float* __restrict__ pctx)
{
    const int ch = blockIdx.x;   // 32 chunks x 256 tokens
    const int h  = blockIdx.y;   // 8 heads
    const int tid = threadIdx.x, w = tid >> 6, lane = tid & 63;
    const int fr = lane & 15, fq = lane >> 4;
    __shared__ unsigned short tr[4][2][4096];   // 64 KiB; reused as fp32 scratch
    __shared__ float redm[4][64], reds[4][64], cmx[64], crc[64];

    // step A: column softmax stats for cols h*64 + (0..63)
    {
        const int c = tid & 63, q = tid >> 6;
        const int col = h * 64 + c;
        float m = -1e30f;
        for (int r = 0; r < 32; ++r) m = fmaxf(m, pmax[(q * 32 + r) * 512 + col]);
        float s = 0.f;
        for (int r = 0; r < 32; ++r)
            s += psum[(q * 32 + r) * 512 + col] * __expf(pmax[(q * 32 + r) * 512 + col] - m);
        redm[q][c] = m; reds[q][c] = s;
    }
    __syncthreads();
    if (tid < 64) {
        float m = fmaxf(fmaxf(redm[0][tid], redm[1][tid]), fmaxf(redm[2][tid], redm[3][tid]));
        float s = 0.f;
        #pragma unroll
        for (int q = 0; q < 4; ++q) s += reds[q][tid] * __expf(redm[q][tid] - m);
        cmx[tid] = m; crc[tid] = 1.f / s;
    }
    __syncthreads();

    // step B: ksm compute + transposed LDS staging + coalesced ksm write
    char* kt = (char*)&tr[w][0][0];
    char* vt = (char*)&tr[w][1][0];
    const int nbase = ch * 256 + w * 64;
    #pragma unroll
    for (int j = 0; j < 8; ++j) {
        bf16x8 kv = *(const bf16x8*)(kbf + (size_t)(nbase + lane) * 512 + h * 64 + j * 8);
        bf16x8 vv = *(const bf16x8*)(vbf + (size_t)(nbase + lane) * 512 + h * 64 + j * 8);
        unsigned short ko[8];
        #pragma unroll
        for (int e = 0; e < 8; ++e) {
            int k = j * 8 + e;
            float x = __expf(bf2f(((const unsigned short*)&kv)[e]) - cmx[k]) * crc[k];
            unsigned short us = f2bf(x);
            ko[e] = us;
            int byte = (k * 128 + lane * 2) ^ (e << 4);   // k&7 == e
            *(unsigned short*)(kt + byte) = us;
            *(unsigned short*)(vt + byte) = ((const unsigned short*)&vv)[e];
        }
        *(uint4*)(ksm + (size_t)(nbase + lane) * 512 + h * 64 + j * 8) = *(const uint4*)ko;
    }
    asm volatile("s_waitcnt lgkmcnt(0)" ::: "memory");
    __builtin_amdgcn_sched_barrier(0);

    f32x4 acc[4][4] = {};
    #pragma unroll
    for (int ks = 0; ks < 2; ++ks) {
        bf16x8 a[4], b[4];
        #pragma unroll
        for (int mf = 0; mf < 4; ++mf) {
            int row  = mf * 16 + fr;
            int byte = (row * 128 + (ks * 4 + fq) * 16) ^ ((row & 7) << 4);
            a[mf] = *(const bf16x8*)(kt + byte);
            b[mf] = *(const bf16x8*)(vt + byte);
        }
        #pragma unroll
        for (int mf = 0; mf < 4; ++mf)
            #pragma unroll
            for (int nf = 0; nf < 4; ++nf)
                acc[mf][nf] = __builtin_amdgcn_mfma_f32_16x16x32_bf16(a[mf], b[nf], acc[mf][nf], 0, 0, 0);
    }

    // cross-wave reduce through LDS (reuse tr), swizzled
    float* red = (float*)&tr[w][0][0];   // 4096 floats
    #pragma unroll
    for (int mf = 0; mf < 4; ++mf)
        #pragma unroll
        for (int nf = 0; nf < 4; ++nf)
            #pragma unroll
            for (int r = 0; r < 4; ++r) {
                int lr = mf * 16 + fq * 4 + r;
                int lc = (nf * 16 + fr) ^ (((lr >> 2) & 1) << 4);
                red[lr * 64 + lc] = acc[mf][nf][r];
            }
    __syncthreads();
    const float* rbase = (const float*)&tr[0][0][0];
    float* out = pctx + (size_t)(ch * 8 + h) * 4096;
    #pragma unroll
    for (int it = 0; it < 16; ++it) {
        int e = it * 256 + tid;
        int lr = e >> 6;
        int ph = (lr * 64) + ((e & 63) ^ (((lr >> 2) & 1) << 4));
        float s = rbase[ph] + rbase[4096 + ph] + rbase[8192 + ph] + rbase[12288 + ph];
        out[e] = s;
    }
}

// ---------------- mtred: context_reduce + mt fused ----------------
// block b: hk = b>>1, o = (b&1)*256 + tid. Threads 0..63 rebuild ctx row
// (reduce 32 pctx partials) into LDS; then coalesced Wr dot.
__global__ void mtred_k(const float* __restrict__ pctx, const float* __restrict__ Wr,
                        unsigned short* __restrict__ Mt) {
    __shared__ float cr[64];
    const int b = blockIdx.x;            // 1024
    const int hk = b >> 1;
    const int o  = (b & 1) * 256 + threadIdx.x;
    const int h = hk >> 6, k = hk & 63;
    if (threadIdx.x < 64) {
        float s = 0.f;
        for (int p = 0; p < 32; ++p)
            s += pctx[(size_t)(p * 8 + h) * 4096 + k * 64 + threadIdx.x];
        cr[threadIdx.x] = s;
    }
    __syncthreads();
    const float* wp = Wr + (size_t)(h * 64) * 512 + o;
    float s = 0.f;
    #pragma unroll
    for (int j = 0; j < 64; ++j)
        s += cr[j] * wp[(size_t)j * 512];
    Mt[(size_t)o * 512 + hk] = f2bf(s);
}

// ---------------- scores + attention merged GEMM ----------------
// blocks 0..255: attention = qsm @ Mt^T + br -> attn_out (N=512)
// blocks 256..4351: scores = 0.125 * qsm @ ksm^T -> scores_out (N=8192), XCD swizzle
__global__ __launch_bounds__(256) void scores_attn_k(
    const unsigned short* __restrict__ qsm, const unsigned short* __restrict__ ksm,
    const unsigned short* __restrict__ Mt, const float* __restrict__ br,
    float* __restrict__ attn_out, float* __restrict__ scores_out)
{
    __shared__ unsigned short sA[128 * 32];
    __shared__ unsigned short sB[128 * 32];
    const int tid  = threadIdx.x;
    const int wid  = tid >> 6;
    const int lane = tid & 63;
    const int wr = (wid >> 1) * 64;
    const int wc = (wid & 1) * 64;
    const int fr = lane & 15;
    const int fq = lane >> 4;
    const int srow = lane >> 2;
    const int scol = (lane & 3) * 8;

    const bool is_attn = blockIdx.x < 256;
    int row0, col0;
    const unsigned short* Bt;
    if (is_attn) {
        const int bx = blockIdx.x;
        col0 = (bx & 3) * 128;
        row0 = (bx >> 2) * 128;
        Bt = Mt;
    } else {
        int g = blockIdx.x - 256;                 // 0..4095
        g = (g & 7) * 512 + (g >> 3);             // bijective XCD swizzle
        row0 = ((g & 7) + ((g >> 9) << 3)) * 128;
        col0 = ((g >> 3) & 63) * 128;
        Bt = ksm;
    }

    f32x4 acc[4][4] = {};

    for (int kt = 0; kt < 16; ++kt) {
        const int k0 = kt << 5;
        __syncthreads();
        #pragma unroll
        for (int s = 0; s < 2; ++s) {
            const int seg = wid * 2 + s;
            const unsigned short* gA = qsm + (size_t)(row0 + seg * 16 + srow) * 512 + k0 + scol;
            __builtin_amdgcn_global_load_lds(
                (const __attribute__((address_space(1))) void*)gA,
                (__attribute__((address_space(3))) void*)(sA + seg * 512), 16, 0, 0);
            const unsigned short* gB = Bt + (size_t)(col0 + seg * 16 + srow) * 512 + k0 + scol;
            __builtin_amdgcn_global_load_lds(
                (const __attribute__((address_space(1))) void*)gB,
                (__attribute__((address_space(3))) void*)(sB + seg * 512), 16, 0, 0);
        }
        __syncthreads();

        bf16x8 av[4], bfrag[4];
        #pragma unroll
        for (int m = 0; m < 4; ++m)
            av[m] = *(const bf16x8*)(sA + (wr + m * 16 + fr) * 32 + fq * 8);
        #pragma unroll
        for (int n = 0; n < 4; ++n)
            bfrag[n] = *(const bf16x8*)(sB + (wc + n * 16 + fr) * 32 + fq * 8);
        #pragma unroll
        for (int m = 0; m < 4; ++m)
            #pragma unroll
            for (int n = 0; n < 4; ++n)
                acc[m][n] = __builtin_amdgcn_mfma_f32_16x16x32_bf16(av[m], bfrag[n], acc[m][n], 0, 0, 0);
    }

    if (is_attn) {
        #pragma unroll
        for (int n = 0; n < 4; ++n) {
            const int col = col0 + wc + n * 16 + fr;
            const float bval = br[col];
            #pragma unroll
            for (int m = 0; m < 4; ++m) {
                #pragma unroll
                for (int r = 0; r < 4; ++r) {
                    const int row = row0 + wr + m * 16 + fq * 4 + r;
                    __builtin_nontemporal_store(acc[m][n][r] + bval, &attn_out[(size_t)row * 512 + col]);
                }
            }
        }
    } else {
        #pragma unroll
        for (int n = 0; n < 4; ++n) {
            const int col = col0 + wc + n * 16 + fr;
            #pragma unroll
            for (int m = 0; m < 4; ++m) {
                #pragma unroll
                for (int r = 0; r < 4; ++r) {
                    const int row = row0 + wr + m * 16 + fq * 4 + r;
                    __builtin_nontemporal_store(acc[m][n][r] * 0.125f, &scores_out[(size_t)row * SC_N + col]);
                }
            }
        }
    }
}

// ---------------- launch ----------------
extern "C" void kernel_launch(void* const* d_in, const int* in_sizes, int n_in,
                              void* d_out, int out_size, void* d_ws, size_t ws_size,
                              hipStream_t stream) {
    const float* input = (const float*)d_in[0];
    const float* Wk = (const float*)d_in[1];
    const float* bk = (const float*)d_in[2];
    const float* Wq = (const float*)d_in[3];
    const float* bq = (const float*)d_in[4];
    const float* Wv = (const float*)d_in[5];
    const float* bv = (const float*)d_in[6];
    const float* Wr = (const float*)d_in[7];
    const float* br = (const float*)d_in[8];

    char* ws = (char*)d_ws;
    unsigned short* inp_bf = (unsigned short*)ws;  ws += (size_t)NT * CD * 2;
    unsigned short* Wt     = (unsigned short*)ws;  ws += (size_t)1536 * 512 * 2;
    float* biaskqv         = (float*)ws;           ws += 1536 * 4;
    unsigned short* kbf    = (unsigned short*)ws;  ws += (size_t)NT * CD * 2;
    unsigned short* qsm    = (unsigned short*)ws;  ws += (size_t)NT * CD * 2;
    unsigned short* vbf    = (unsigned short*)ws;  ws += (size_t)NT * CD * 2;
    unsigned short* ksm    = (unsigned short*)ws;  ws += (size_t)NT * CD * 2;
    float* pmax            = (float*)ws;           ws += 128 * 512 * 4;
    float* psum            = (float*)ws;           ws += 128 * 512 * 4;
    float* pctx            = (float*)ws;           ws += (size_t)32 * 8 * 4096 * 4;
    unsigned short* Mt     = (unsigned short*)ws;  ws += (size_t)512 * 512 * 2;

    float* attn_out   = (float*)d_out;
    float* scores_out = (float*)d_out + (size_t)NT * CD;

    prep_k<<<7168, 256, 0, stream>>>((const float4*)input, inp_bf,
                                     Wk, Wq, Wv, bk, bq, bv, Wt, biaskqv);

    kqv_gemm_k<<<dim3(12, 64), 256, 0, stream>>>(inp_bf, Wt, biaskqv,
                                                 kbf, qsm, vbf, pmax, psum);

    ksmctx_k<<<dim3(32, 8), 256, 0, stream>>>(kbf, vbf, pmax, psum, ksm, pctx);

    mtred_k<<<1024, 256, 0, stream>>>(pctx, Wr, Mt);

    scores_attn_k<<<4352, 256, 0, stream>>>(qsm, ksm, Mt, br, attn_out, scores_out);
}